// Round 1
// baseline (1608.938 us; speedup 1.0000x reference)
//
#include <hip/hip_runtime.h>

#define NSEG 4096

// ---- monotone float <-> uint mapping for atomic max over floats ----
__device__ __forceinline__ unsigned int f2ord(float f) {
  unsigned int u = __float_as_uint(f);
  return (u & 0x80000000u) ? ~u : (u | 0x80000000u);
}
__device__ __forceinline__ float ord2f(unsigned int u) {
  return (u & 0x80000000u) ? __uint_as_float(u ^ 0x80000000u)
                           : __uint_as_float(~u);
}

__global__ void init_seg(unsigned int* __restrict__ smax, float* __restrict__ ssum) {
  int i = blockIdx.x * blockDim.x + threadIdx.x;
  if (i < NSEG) { smax[i] = 0u; ssum[i] = 0.0f; }
}

// Y = X @ W ; X: nrows x 128 row-major, W: 128 x 128 row-major.
// Block: 256 threads, 64 rows per block. LDS pitch 132 breaks the
// stride-512-float bank alias (would be 4-way) down to free 2-way.
__global__ __launch_bounds__(256) void proj_gemm(const float* __restrict__ X,
                                                 const float* __restrict__ W,
                                                 float* __restrict__ Y, int nrows) {
  __shared__ float xs[64 * 132];
  const int tid = threadIdx.x;
  const long base = (long)blockIdx.x * (64 * 128);
  const long total = (long)nrows * 128;
  // stage 64x128 X tile into LDS (guarded for the partial last block)
  #pragma unroll
  for (int i = 0; i < 8; ++i) {
    int idx = tid + i * 256;     // float4 index within tile (2048 total)
    int row = idx >> 5;          // 32 float4 per row
    int col4 = idx & 31;
    long ge = base + (long)idx * 4;
    float4 v = make_float4(0.f, 0.f, 0.f, 0.f);
    if (ge + 3 < total) v = *(const float4*)(X + ge);
    float* dst = xs + row * 132 + col4 * 4;
    dst[0] = v.x; dst[1] = v.y; dst[2] = v.z; dst[3] = v.w;
  }
  __syncthreads();
  const int ty = tid >> 4;   // 0..15 -> rows ty*4 .. +3
  const int tx = tid & 15;   // cols tx*4..+3 and 64+tx*4..+3 (2-way bank alias, free)
  const int r0 = ty * 4;
  const int c0 = tx * 4;
  float acc0[4][4] = {};
  float acc1[4][4] = {};
  const float* Wc = W + c0;
  #pragma unroll 4
  for (int k = 0; k < 128; ++k) {
    float4 w0 = *(const float4*)(Wc + k * 128);
    float4 w1 = *(const float4*)(Wc + k * 128 + 64);
    float xv[4];
    #pragma unroll
    for (int r = 0; r < 4; ++r) xv[r] = xs[(r0 + r) * 132 + k];
    #pragma unroll
    for (int r = 0; r < 4; ++r) {
      acc0[r][0] += xv[r] * w0.x; acc0[r][1] += xv[r] * w0.y;
      acc0[r][2] += xv[r] * w0.z; acc0[r][3] += xv[r] * w0.w;
      acc1[r][0] += xv[r] * w1.x; acc1[r][1] += xv[r] * w1.y;
      acc1[r][2] += xv[r] * w1.z; acc1[r][3] += xv[r] * w1.w;
    }
  }
  const long rowBase = (long)blockIdx.x * 64 + r0;
  #pragma unroll
  for (int r = 0; r < 4; ++r) {
    long row = rowBase + r;
    if (row < nrows) {
      *(float4*)(Y + row * 128 + c0) =
          make_float4(acc0[r][0], acc0[r][1], acc0[r][2], acc0[r][3]);
      *(float4*)(Y + row * 128 + 64 + c0) =
          make_float4(acc1[r][0], acc1[r][1], acc1[r][2], acc1[r][3]);
    }
  }
}

// One wave per edge: gather both projected rows (coalesced 512B each),
// PReLU + dot with mlp_W, wave-reduce, write alpha, atomic seg-max (fused).
__global__ __launch_bounds__(256) void edge_alpha(
    const float* __restrict__ xjp, const float* __restrict__ xip,
    const int* __restrict__ ei, const int* __restrict__ batch,
    const float* __restrict__ bias, const float* __restrict__ mlpW,
    const float* __restrict__ prelu_w, const float* __restrict__ mlp_b,
    float* __restrict__ alpha, unsigned int* __restrict__ smax, int E) {
  const int wid = (int)((blockIdx.x * (long)blockDim.x + threadIdx.x) >> 6);
  const int lane = threadIdx.x & 63;
  if (wid >= E) return;
  const int src = ei[wid];
  const int dst = ei[E + wid];
  const float pw = prelu_w[0];
  float2 a = *(const float2*)(xjp + (long)src * 128 + lane * 2);
  float2 b = *(const float2*)(xip + (long)dst * 128 + lane * 2);
  float2 bi = *(const float2*)(bias + lane * 2);
  float2 w = *(const float2*)(mlpW + lane * 2);
  float h0 = a.x + b.x + bi.x;
  float h1 = a.y + b.y + bi.y;
  h0 = h0 >= 0.f ? h0 : pw * h0;
  h1 = h1 >= 0.f ? h1 : pw * h1;
  float p = h0 * w.x + h1 * w.y;
  #pragma unroll
  for (int off = 32; off > 0; off >>= 1) p += __shfl_xor(p, off, 64);
  if (lane == 0) {
    float av = p + mlp_b[0];
    alpha[wid] = av;
    atomicMax(&smax[batch[wid]], f2ord(av));
  }
}

__global__ void exp_sum(const float* __restrict__ alpha, const int* __restrict__ batch,
                        const unsigned int* __restrict__ smax, float* __restrict__ ev,
                        float* __restrict__ ssum, int E) {
  int e = blockIdx.x * blockDim.x + threadIdx.x;
  if (e >= E) return;
  int b = batch[e];
  float m = ord2f(smax[b]);
  float x = expf(alpha[e] - m);
  ev[e] = x;
  atomicAdd(&ssum[b], x);
}

__global__ void normalize_k(const float* __restrict__ ev, const int* __restrict__ batch,
                            const float* __restrict__ ssum, float* __restrict__ out, int E) {
  int e = blockIdx.x * blockDim.x + threadIdx.x;
  if (e >= E) return;
  out[e] = ev[e] / (ssum[batch[e]] + 1e-16f);
}

extern "C" void kernel_launch(void* const* d_in, const int* in_sizes, int n_in,
                              void* d_out, int out_size, void* d_ws, size_t ws_size,
                              hipStream_t stream) {
  const float* x_j      = (const float*)d_in[0];
  const float* x_i      = (const float*)d_in[1];
  const int*   edge_idx = (const int*)d_in[2];
  const int*   batch    = (const int*)d_in[3];
  const float* w_j      = (const float*)d_in[4];
  const float* w_i      = (const float*)d_in[5];
  const float* bias     = (const float*)d_in[6];
  const float* prelu_w  = (const float*)d_in[7];
  const float* mlp_W    = (const float*)d_in[8];
  const float* mlp_b    = (const float*)d_in[9];
  const int nnodes = in_sizes[0] / 128;
  const int E = in_sizes[3];

  float* xjp  = (float*)d_ws;
  float* xip  = xjp + (size_t)nnodes * 128;
  float* alpha = xip + (size_t)nnodes * 128;
  float* ev    = alpha + E;
  float* ssum  = ev + E;
  unsigned int* smax = (unsigned int*)(ssum + NSEG);

  hipLaunchKernelGGL(init_seg, dim3(16), dim3(256), 0, stream, smax, ssum);

  int gblocks = (nnodes + 63) / 64;
  hipLaunchKernelGGL(proj_gemm, dim3(gblocks), dim3(256), 0, stream, x_j, w_j, xjp, nnodes);
  hipLaunchKernelGGL(proj_gemm, dim3(gblocks), dim3(256), 0, stream, x_i, w_i, xip, nnodes);

  int eblocks = (E + 3) / 4;  // 4 waves (edges) per 256-thread block
  hipLaunchKernelGGL(edge_alpha, dim3(eblocks), dim3(256), 0, stream,
                     xjp, xip, edge_idx, batch, bias, mlp_W, prelu_w, mlp_b,
                     alpha, smax, E);

  int tblocks = (E + 255) / 256;
  hipLaunchKernelGGL(exp_sum, dim3(tblocks), dim3(256), 0, stream,
                     alpha, batch, smax, ev, ssum, E);
  hipLaunchKernelGGL(normalize_k, dim3(tblocks), dim3(256), 0, stream,
                     ev, batch, ssum, (float*)d_out, E);
}

// Round 2
// 393.751 us; speedup vs baseline: 4.0862x; 4.0862x over previous
//
#include <hip/hip_runtime.h>
#include <float.h>

#define NSEG 4096
#define CAP 2048   // max edges/segment held in LDS (binomial(1M,1/4096) max ~330)

// ---- segment boundaries: segs[b] = first edge index with batch >= b ----
__global__ void seg_bounds(const int* __restrict__ batch, int* __restrict__ segs, int E) {
  int b = blockIdx.x * blockDim.x + threadIdx.x;
  if (b > NSEG) return;
  int lo = 0, hi = E;
  while (lo < hi) { int mid = (lo + hi) >> 1; if (batch[mid] < b) lo = mid + 1; else hi = mid; }
  segs[b] = lo;
}

// Y = X @ W (+bias for grid.y==1); X: nrows x 128, W: 128 x 128 row-major.
// 64 rows/block, LDS pitch 132 (breaks stride-512 alias to free 2-way).
__global__ __launch_bounds__(256) void proj_gemm(
    const float* __restrict__ Xj, const float* __restrict__ Wj,
    const float* __restrict__ Xi, const float* __restrict__ Wi,
    const float* __restrict__ bias,
    float* __restrict__ Yj, float* __restrict__ Yi, int nrows) {
  const int which = blockIdx.y;
  const float* X = which ? Xi : Xj;
  const float* W = which ? Wi : Wj;
  float* Y = which ? Yi : Yj;

  __shared__ float xs[64 * 132];
  const int tid = threadIdx.x;
  const long base = (long)blockIdx.x * (64 * 128);
  const long total = (long)nrows * 128;
  #pragma unroll
  for (int i = 0; i < 8; ++i) {
    int idx = tid + i * 256;
    int row = idx >> 5;
    int col4 = idx & 31;
    long ge = base + (long)idx * 4;
    float4 v = make_float4(0.f, 0.f, 0.f, 0.f);
    if (ge + 3 < total) v = *(const float4*)(X + ge);
    float* dst = xs + row * 132 + col4 * 4;
    dst[0] = v.x; dst[1] = v.y; dst[2] = v.z; dst[3] = v.w;
  }
  __syncthreads();
  const int ty = tid >> 4;
  const int tx = tid & 15;
  const int r0 = ty * 4;
  const int c0 = tx * 4;
  float acc0[4][4] = {};
  float acc1[4][4] = {};
  const float* Wc = W + c0;
  #pragma unroll 4
  for (int k = 0; k < 128; ++k) {
    float4 w0 = *(const float4*)(Wc + k * 128);
    float4 w1 = *(const float4*)(Wc + k * 128 + 64);
    float xv[4];
    #pragma unroll
    for (int r = 0; r < 4; ++r) xv[r] = xs[(r0 + r) * 132 + k];
    #pragma unroll
    for (int r = 0; r < 4; ++r) {
      acc0[r][0] += xv[r] * w0.x; acc0[r][1] += xv[r] * w0.y;
      acc0[r][2] += xv[r] * w0.z; acc0[r][3] += xv[r] * w0.w;
      acc1[r][0] += xv[r] * w1.x; acc1[r][1] += xv[r] * w1.y;
      acc1[r][2] += xv[r] * w1.z; acc1[r][3] += xv[r] * w1.w;
    }
  }
  float4 b0 = make_float4(0.f, 0.f, 0.f, 0.f), b1 = b0;
  if (which) { b0 = *(const float4*)(bias + c0); b1 = *(const float4*)(bias + 64 + c0); }
  const long rowBase = (long)blockIdx.x * 64 + r0;
  #pragma unroll
  for (int r = 0; r < 4; ++r) {
    long row = rowBase + r;
    if (row < nrows) {
      *(float4*)(Y + row * 128 + c0) =
          make_float4(acc0[r][0] + b0.x, acc0[r][1] + b0.y, acc0[r][2] + b0.z, acc0[r][3] + b0.w);
      *(float4*)(Y + row * 128 + 64 + c0) =
          make_float4(acc1[r][0] + b1.x, acc1[r][1] + b1.y, acc1[r][2] + b1.z, acc1[r][3] + b1.w);
    }
  }
}

// One block per segment. Phase 1: alpha per edge (half-wave/edge, dual-edge
// unrolled -> 4 gathers in flight per wave). Phase 2-4: block softmax. No atomics.
__global__ __launch_bounds__(256) void seg_softmax(
    const float* __restrict__ xjp, const float* __restrict__ xip,
    const int* __restrict__ ei, const int* __restrict__ segs,
    const float* __restrict__ mlpW, const float* __restrict__ prelu_w,
    const float* __restrict__ mlp_b, float* __restrict__ out, int E) {
  const int start = segs[blockIdx.x];
  const int end = segs[blockIdx.x + 1];
  const int cnt = end - start;
  if (cnt <= 0) return;

  __shared__ float aS[CAP];
  __shared__ float red[8];

  const int tid = threadIdx.x;
  const int lane = tid & 63;
  const int sl = lane & 31;          // lane within half-wave
  const int slot = tid >> 5;         // 8 half-wave edge slots per block
  const int wid = tid >> 6;

  const float4 w = *(const float4*)(mlpW + sl * 4);
  const float pw = prelu_w[0];
  const float mb = mlp_b[0];
  const bool useLds = (cnt <= CAP);

  // ---- phase 1: alpha ----
  for (int e = start + slot; e < end; e += 16) {
    int e2 = e + 8;
    bool v2 = (e2 < end);
    int s1 = ei[e], d1 = ei[E + e];
    int s2 = v2 ? ei[e2] : s1;
    int d2 = v2 ? ei[E + e2] : d1;
    float4 a1 = *(const float4*)(xjp + (long)s1 * 128 + sl * 4);
    float4 b1 = *(const float4*)(xip + (long)d1 * 128 + sl * 4);
    float4 a2 = *(const float4*)(xjp + (long)s2 * 128 + sl * 4);
    float4 b2 = *(const float4*)(xip + (long)d2 * 128 + sl * 4);

    float h0 = a1.x + b1.x, h1 = a1.y + b1.y, h2 = a1.z + b1.z, h3 = a1.w + b1.w;
    h0 = h0 >= 0.f ? h0 : pw * h0; h1 = h1 >= 0.f ? h1 : pw * h1;
    h2 = h2 >= 0.f ? h2 : pw * h2; h3 = h3 >= 0.f ? h3 : pw * h3;
    float p1 = h0 * w.x + h1 * w.y + h2 * w.z + h3 * w.w;

    float g0 = a2.x + b2.x, g1 = a2.y + b2.y, g2 = a2.z + b2.z, g3 = a2.w + b2.w;
    g0 = g0 >= 0.f ? g0 : pw * g0; g1 = g1 >= 0.f ? g1 : pw * g1;
    g2 = g2 >= 0.f ? g2 : pw * g2; g3 = g3 >= 0.f ? g3 : pw * g3;
    float p2 = g0 * w.x + g1 * w.y + g2 * w.z + g3 * w.w;

    #pragma unroll
    for (int off = 1; off < 32; off <<= 1) {
      p1 += __shfl_xor(p1, off, 64);
      p2 += __shfl_xor(p2, off, 64);
    }
    if (sl == 0) {
      float av1 = p1 + mb;
      if (useLds) aS[e - start] = av1; else out[e] = av1;
      if (v2) {
        float av2 = p2 + mb;
        if (useLds) aS[e2 - start] = av2; else out[e2] = av2;
      }
    }
  }
  __syncthreads();

  // ---- phase 2: block max ----
  float m = -FLT_MAX;
  if (useLds) { for (int i = tid; i < cnt; i += 256) m = fmaxf(m, aS[i]); }
  else        { for (int i = tid; i < cnt; i += 256) m = fmaxf(m, out[start + i]); }
  #pragma unroll
  for (int off = 1; off < 64; off <<= 1) m = fmaxf(m, __shfl_xor(m, off, 64));
  if (lane == 0) red[wid] = m;
  __syncthreads();
  m = fmaxf(fmaxf(red[0], red[1]), fmaxf(red[2], red[3]));

  // ---- phase 3: exp + block sum ----
  float s = 0.f;
  if (useLds) {
    for (int i = tid; i < cnt; i += 256) { float x = expf(aS[i] - m); aS[i] = x; s += x; }
  } else {
    for (int i = tid; i < cnt; i += 256) { float x = expf(out[start + i] - m); out[start + i] = x; s += x; }
  }
  #pragma unroll
  for (int off = 1; off < 64; off <<= 1) s += __shfl_xor(s, off, 64);
  if (lane == 0) red[4 + wid] = s;
  __syncthreads();
  s = (red[4] + red[5]) + (red[6] + red[7]);

  // ---- phase 4: normalize + write ----
  const float inv = 1.0f / (s + 1e-16f);
  if (useLds) { for (int i = tid; i < cnt; i += 256) out[start + i] = aS[i] * inv; }
  else        { for (int i = tid; i < cnt; i += 256) out[start + i] *= inv; }
}

extern "C" void kernel_launch(void* const* d_in, const int* in_sizes, int n_in,
                              void* d_out, int out_size, void* d_ws, size_t ws_size,
                              hipStream_t stream) {
  const float* x_j      = (const float*)d_in[0];
  const float* x_i      = (const float*)d_in[1];
  const int*   edge_idx = (const int*)d_in[2];
  const int*   batch    = (const int*)d_in[3];
  const float* w_j      = (const float*)d_in[4];
  const float* w_i      = (const float*)d_in[5];
  const float* bias     = (const float*)d_in[6];
  const float* prelu_w  = (const float*)d_in[7];
  const float* mlp_W    = (const float*)d_in[8];
  const float* mlp_b    = (const float*)d_in[9];
  const int nnodes = in_sizes[0] / 128;
  const int E = in_sizes[3];

  float* xjp = (float*)d_ws;
  float* xip = xjp + (size_t)nnodes * 128;
  int* segs  = (int*)(xip + (size_t)nnodes * 128);

  hipLaunchKernelGGL(seg_bounds, dim3((NSEG + 1 + 255) / 256), dim3(256), 0, stream,
                     batch, segs, E);

  int gblocks = (nnodes + 63) / 64;
  hipLaunchKernelGGL(proj_gemm, dim3(gblocks, 2), dim3(256), 0, stream,
                     x_j, w_j, x_i, w_i, bias, xjp, xip, nnodes);

  hipLaunchKernelGGL(seg_softmax, dim3(NSEG), dim3(256), 0, stream,
                     xjp, xip, edge_idx, segs, mlp_W, prelu_w, mlp_b,
                     (float*)d_out, E);
}